// Round 1
// baseline (287.610 us; speedup 1.0000x reference)
//
#include <hip/hip_runtime.h>
#include <stdint.h>

typedef unsigned short u16;
typedef unsigned int   u32;
typedef __attribute__((ext_vector_type(8))) short bf16x8;
typedef __attribute__((ext_vector_type(4))) float f32x4;

#define EPS 1e-3f
#define NB 32
#define HW 56
#define CI 256
#define CM 128
#define PIX (NB*HW*HW)   // 100352

__device__ __forceinline__ float asf(u32 i){ union{u32 u; float f;} t; t.u=i; return t.f; }
__device__ __forceinline__ u16 f2bf(float f){
  union{float f; u32 u;} t; t.f = f;
  u32 x = t.u;
  return (u16)((x + 0x7fffu + ((x>>16)&1u)) >> 16);   // RNE
}

// ---------------- prep: MFMA-fragment-swizzled bf16 weights + BN fold ----------------
__global__ __launch_bounds__(256) void kprep(
    const float* __restrict__ w1, const float* __restrict__ b1, const float* __restrict__ g1,
    const float* __restrict__ be1, const float* __restrict__ m1, const float* __restrict__ v1,
    const float* __restrict__ b2, const float* __restrict__ g2,
    const float* __restrict__ be2, const float* __restrict__ m2, const float* __restrict__ v2,
    const float* __restrict__ w3,
    u16* __restrict__ w1s, u16* __restrict__ w3s,
    float* __restrict__ A1, float* __restrict__ B1,
    float* __restrict__ A2, float* __restrict__ B2){
  int i = blockIdx.x*256 + threadIdx.x;
  if (i < 32768){
    { // w1s: t(8) x kt(8) x lane(64) x 8
      int j = i & 7, lane = (i >> 3) & 63, kt = (i >> 9) & 7, t = i >> 12;
      int col = lane & 15, quad = lane >> 4;
      int n = t*16 + col, k = kt*32 + quad*8 + j;
      w1s[i] = f2bf(w1[k*CM + n]);
    }
    { // w3s: t(16) x kc(4) x lane(64) x 8
      int j = i & 7, lane = (i >> 3) & 63, kc = (i >> 9) & 3, t = i >> 11;
      int col = lane & 15, quad = lane >> 4;
      int n = t*16 + col, k = kc*32 + quad*8 + j;
      w3s[i] = f2bf(w3[k*CI + n]);
    }
  }
  if (i < 128){
    float s1 = g1[i] * rsqrtf(v1[i] + EPS);
    A1[i] = s1;
    B1[i] = b1[i]*s1 + be1[i] - m1[i]*s1;
    float s2 = g2[i] * rsqrtf(v2[i] + EPS);
    A2[i] = s2;
    B2[i] = b2[i]*s2 + be2[i] - m2[i]*s2;
  }
}

// ---------------- conv1 1x1 256->128 + BN + ReLU ----------------
// v2: LDS-free A path. Wave wv owns m-tiles {2wv, 2wv+1} x all 8 n-tiles.
// A-fragments read directly from global x (L1/L2-served, each value cvt'd once),
// B-fragments from swizzled w1s in L2. NO barriers in the K loop.
// LDS only for the coalesced bf16 repack of h1 (34816 B -> 4 blocks/CU).
__global__ __launch_bounds__(256, 3) void k1(const float* __restrict__ x,
    const u16* __restrict__ w1s, const float* __restrict__ A1v,
    const float* __restrict__ B1v, u16* __restrict__ h1){
  __shared__ __align__(16) u16 outw[128*136];
  const int tid  = threadIdx.x;
  const int lane = tid & 63, wv = tid >> 6;
  const int col  = lane & 15, quad = lane >> 4;
  const long p0 = (long)blockIdx.x * 128;
  f32x4 acc[2][8];
  #pragma unroll
  for (int a = 0; a < 2; a++)
    #pragma unroll
    for (int b = 0; b < 8; b++){ acc[a][b][0]=0.f; acc[a][b][1]=0.f; acc[a][b][2]=0.f; acc[a][b][3]=0.f; }
  const float* xb = x + (p0 + wv*32 + col)*CI + quad*8;
  for (int kt = 0; kt < 8; kt++){
    bf16x8 bfr[8];
    #pragma unroll
    for (int nt = 0; nt < 8; nt++)
      bfr[nt] = *(const bf16x8*)(w1s + (size_t)((nt*8 + kt)*64 + lane)*8);
    #pragma unroll
    for (int mt = 0; mt < 2; mt++){
      const float* xp = xb + mt*16*CI + kt*32;
      float4 v0 = *(const float4*)xp;
      float4 v1 = *(const float4*)(xp + 4);
      union{ bf16x8 v; u32 w[4]; } af;
      af.w[0] = (u32)f2bf(v0.x) | ((u32)f2bf(v0.y) << 16);
      af.w[1] = (u32)f2bf(v0.z) | ((u32)f2bf(v0.w) << 16);
      af.w[2] = (u32)f2bf(v1.x) | ((u32)f2bf(v1.y) << 16);
      af.w[3] = (u32)f2bf(v1.z) | ((u32)f2bf(v1.w) << 16);
      #pragma unroll
      for (int nt = 0; nt < 8; nt++)
        acc[mt][nt] = __builtin_amdgcn_mfma_f32_16x16x32_bf16(af.v, bfr[nt], acc[mt][nt], 0, 0, 0);
    }
  }
  // epilogue: BN + ReLU -> bf16, repack via LDS, vector store
  #pragma unroll
  for (int nt = 0; nt < 8; nt++){
    int n = nt*16 + col;
    float a1 = A1v[n], b1v = B1v[n];
    #pragma unroll
    for (int mt = 0; mt < 2; mt++)
      #pragma unroll
      for (int reg = 0; reg < 4; reg++){
        int m = wv*32 + mt*16 + quad*4 + reg;
        outw[m*136 + n] = f2bf(fmaxf(acc[mt][nt][reg]*a1 + b1v, 0.f));
      }
  }
  __syncthreads();
  #pragma unroll
  for (int r = 0; r < 8; r++){
    int idx = r*256 + tid;
    int m = idx >> 4, u4 = idx & 15;
    uint4 v = *(const uint4*)(outw + m*136 + u4*8);
    *(uint4*)(h1 + (p0+m)*CM + u4*8) = v;
  }
}

// ---------------- fused: grouped 3x3 + BN + ReLU + conv3 + bias + residual + ReLU ----------------
// v2: 512 threads (8 waves), LDS overlay (tile/h2t/pre share one region),
// residual-x register prefetch, XCD-aware block swizzle.
// LDS: max region 44352 (tile) + wsh 18432 = 62784 B -> 2 blocks/CU, 16 waves/CU.
#define LSH1 132   // h1 tile stride (u16)
#define LSH2 136   // h2 tile stride (u16)
__global__ __launch_bounds__(512, 4) void k23(const u16* __restrict__ h1,
    const float* __restrict__ w2, const float* __restrict__ A2v,
    const float* __restrict__ B2v, const u16* __restrict__ w3s,
    const float* __restrict__ b3, const float* __restrict__ x,
    float* __restrict__ out){
  __shared__ __align__(16) char smem[3*HW*LSH1*2 + 4608*4];   // 44352 + 18432 = 62784
  u16*  tile = (u16*)smem;                                 // [3][56][132] bf16 (phase A/B)
  u16*  h2t  = (u16*)smem;                                 // [64][136] bf16 (overlay, phase B->C)
  float* pre = (float*)smem;                               // [64][132] f32 (overlay, epilogue)
  float* wsh = (float*)(smem + 3*HW*LSH1*2);               // [4608] f32 w2 (live whole kernel)

  const int tid = threadIdx.x;
  // XCD swizzle: grid 1792 = 8 * 224; XCD k gets 224 consecutive (img,row) blocks.
  const int bid = blockIdx.x;
  const int blk = (bid & 7)*224 + (bid >> 3);
  const int y0 = blk % HW;                 // row within image
  const long p0 = (long)blk * HW;          // first output pixel

  // ---- phase A: stage w2 + h1 rows y0-1..y0+1 ----
  for (int i = tid; i < 1152; i += 512)
    ((float4*)wsh)[i] = ((const float4*)w2)[i];
  #pragma unroll
  for (int r = 0; r < 3; r++){
    const int yy = y0 + r - 1;
    const bool valid = (yy >= 0 && yy < HW);
    const uint4* src = (const uint4*)(h1 + (long)(blk - y0 + yy)*HW*CM);
    for (int i = tid; i < 896; i += 512){
      uint4 v = make_uint4(0u,0u,0u,0u);
      if (valid) v = src[i];
      int px = i >> 4, ch = (i & 15)*8;
      u16* d = tile + (r*HW + px)*LSH1 + ch;
      *(uint2*)d     = make_uint2(v.x, v.y);
      *(uint2*)(d+4) = make_uint2(v.z, v.w);
    }
  }
  __syncthreads();   // sync1: tile+wsh staged

  // ---- residual prefetch, n-half 0: HBM streams under phase-B VALU ----
  float4 xr[4];
  #pragma unroll
  for (int it = 0; it < 4; it++){
    int i = tid + it*512;
    if (i < 1792){
      int m = i >> 5, f4 = i & 31;
      xr[it] = *(const float4*)(x + (p0+m)*CI + f4*4);
    }
  }

  // ---- phase B: grouped 3x3 conv, fp32 VALU, result kept in regs ----
  const int q = tid >> 6, pos = tid & 63;   // q: channel-eighth (wave id), pos: pixel
  const bool act = pos < HW;
  u16 ov[16];
  if (act){
    int ixo[3]; u32 mk[3];
    #pragma unroll
    for (int kx = 0; kx < 3; kx++){
      int c = pos + kx - 1;
      ixo[kx] = (c < 0 ? 0 : (c > 55 ? 55 : c)) * LSH1;
      mk[kx] = (c >= 0 && c < HW) ? 0xffffffffu : 0u;
    }
    #pragma unroll
    for (int gi = 0; gi < 4; gi++){
      const int cb = q*16 + gi*4;
      float a0=0.f, a1=0.f, a2=0.f, a3=0.f;
      #pragma unroll
      for (int ky = 0; ky < 3; ky++){
        const u16* trow = tile + ky*HW*LSH1 + cb;
        #pragma unroll
        for (int kx = 0; kx < 3; kx++){
          uint2 hv = *(const uint2*)(trow + ixo[kx]);
          u32 hx = hv.x & mk[kx], hy = hv.y & mk[kx];
          float i0 = asf(hx<<16), i1 = asf(hx&0xffff0000u);
          float i2 = asf(hy<<16), i3 = asf(hy&0xffff0000u);
          const float* wp = wsh + ((ky*3+kx)*4)*CM + cb;
          float4 w0  = *(const float4*)(wp);
          float4 w1v = *(const float4*)(wp+CM);
          float4 w2v = *(const float4*)(wp+2*CM);
          float4 w3v = *(const float4*)(wp+3*CM);
          a0 += i0*w0.x + i1*w1v.x + i2*w2v.x + i3*w3v.x;
          a1 += i0*w0.y + i1*w1v.y + i2*w2v.y + i3*w3v.y;
          a2 += i0*w0.z + i1*w1v.z + i2*w2v.z + i3*w3v.z;
          a3 += i0*w0.w + i1*w1v.w + i2*w2v.w + i3*w3v.w;
        }
      }
      float av[4] = {a0, a1, a2, a3};
      #pragma unroll
      for (int co = 0; co < 4; co++){
        int c = cb + co;
        ov[gi*4+co] = f2bf(fmaxf(av[co]*A2v[c] + B2v[c], 0.f));
      }
    }
  }
  __syncthreads();   // sync2: ALL tile reads complete (tile region now dead)

  // ---- write h2 into overlay region + zero pad rows ----
  if (act){
    uint4 pk0, pk1;
    pk0.x = (u32)ov[0]  | ((u32)ov[1]<<16);
    pk0.y = (u32)ov[2]  | ((u32)ov[3]<<16);
    pk0.z = (u32)ov[4]  | ((u32)ov[5]<<16);
    pk0.w = (u32)ov[6]  | ((u32)ov[7]<<16);
    pk1.x = (u32)ov[8]  | ((u32)ov[9]<<16);
    pk1.y = (u32)ov[10] | ((u32)ov[11]<<16);
    pk1.z = (u32)ov[12] | ((u32)ov[13]<<16);
    pk1.w = (u32)ov[14] | ((u32)ov[15]<<16);
    u16* op = h2t + pos*LSH2 + q*16;
    *(uint4*)op     = pk0;
    *(uint4*)(op+8) = pk1;
  }
  for (int i = tid; i < 544; i += 512)
    ((u32*)(h2t + 56*LSH2))[i] = 0u;
  __syncthreads();   // sync3: h2t ready

  // ---- phase C: conv3 MFMA. M=64, wave wv owns N=[wv*32, wv*32+32) ----
  const int lane = tid & 63, wv = tid >> 6;
  const int col  = lane & 15, quad = lane >> 4;
  f32x4 acc3[4][2];
  #pragma unroll
  for (int a = 0; a < 4; a++)
    #pragma unroll
    for (int b = 0; b < 2; b++){ acc3[a][b][0]=0.f; acc3[a][b][1]=0.f; acc3[a][b][2]=0.f; acc3[a][b][3]=0.f; }
  float bias[2];
  #pragma unroll
  for (int nt = 0; nt < 2; nt++) bias[nt] = b3[wv*32 + nt*16 + col];
  #pragma unroll
  for (int kc = 0; kc < 4; kc++){
    bf16x8 bfr[2], af[4];
    #pragma unroll
    for (int nt = 0; nt < 2; nt++)
      bfr[nt] = *(const bf16x8*)(w3s + (size_t)(((wv*2+nt)*4 + kc)*64 + lane)*8);
    #pragma unroll
    for (int mt = 0; mt < 4; mt++)
      af[mt] = *(const bf16x8*)(h2t + (mt*16 + col)*LSH2 + kc*32 + quad*8);
    #pragma unroll
    for (int mt = 0; mt < 4; mt++)
      #pragma unroll
      for (int nt = 0; nt < 2; nt++)
        acc3[mt][nt] = __builtin_amdgcn_mfma_f32_16x16x32_bf16(af[mt], bfr[nt], acc3[mt][nt], 0, 0, 0);
  }
  __syncthreads();   // sync4: h2t reads done (region free for pre overlay)

  // ---- epilogue: n-half 0 ----
  if (wv < 4){
    #pragma unroll
    for (int mt = 0; mt < 4; mt++)
      #pragma unroll
      for (int nt = 0; nt < 2; nt++)
        #pragma unroll
        for (int reg = 0; reg < 4; reg++){
          int m = mt*16 + quad*4 + reg;
          pre[m*132 + (wv&3)*32 + nt*16 + col] = acc3[mt][nt][reg] + bias[nt];
        }
  }
  __syncthreads();   // sync5: pre half-0 ready

  // issue n-half-1 residual loads now; they fly during the half-0 store loop
  float4 xr2[4];
  #pragma unroll
  for (int it = 0; it < 4; it++){
    int i = tid + it*512;
    if (i < 1792){
      int m = i >> 5, f4 = i & 31;
      xr2[it] = *(const float4*)(x + (p0+m)*CI + 128 + f4*4);
    }
  }
  #pragma unroll
  for (int it = 0; it < 4; it++){
    int i = tid + it*512;
    if (i < 1792){
      int m = i >> 5, f4 = i & 31;
      float4 pv = *(const float4*)(pre + m*132 + f4*4);
      float4 o;
      o.x = fmaxf(pv.x + xr[it].x, 0.f);
      o.y = fmaxf(pv.y + xr[it].y, 0.f);
      o.z = fmaxf(pv.z + xr[it].z, 0.f);
      o.w = fmaxf(pv.w + xr[it].w, 0.f);
      *(float4*)(out + (p0+m)*CI + f4*4) = o;
    }
  }
  __syncthreads();   // sync6: pre half-0 consumed

  // ---- epilogue: n-half 1 ----
  if (wv >= 4){
    #pragma unroll
    for (int mt = 0; mt < 4; mt++)
      #pragma unroll
      for (int nt = 0; nt < 2; nt++)
        #pragma unroll
        for (int reg = 0; reg < 4; reg++){
          int m = mt*16 + quad*4 + reg;
          pre[m*132 + (wv&3)*32 + nt*16 + col] = acc3[mt][nt][reg] + bias[nt];
        }
  }
  __syncthreads();   // sync7: pre half-1 ready
  #pragma unroll
  for (int it = 0; it < 4; it++){
    int i = tid + it*512;
    if (i < 1792){
      int m = i >> 5, f4 = i & 31;
      float4 pv = *(const float4*)(pre + m*132 + f4*4);
      float4 o;
      o.x = fmaxf(pv.x + xr2[it].x, 0.f);
      o.y = fmaxf(pv.y + xr2[it].y, 0.f);
      o.z = fmaxf(pv.z + xr2[it].z, 0.f);
      o.w = fmaxf(pv.w + xr2[it].w, 0.f);
      *(float4*)(out + (p0+m)*CI + 128 + f4*4) = o;
    }
  }
}

extern "C" void kernel_launch(void* const* d_in, const int* in_sizes, int n_in,
                              void* d_out, int out_size, void* d_ws, size_t ws_size,
                              hipStream_t stream){
  (void)in_sizes; (void)n_in; (void)out_size; (void)ws_size;
  const float* x   = (const float*)d_in[0];
  const float* w1  = (const float*)d_in[1];
  const float* b1  = (const float*)d_in[2];
  const float* g1  = (const float*)d_in[3];
  const float* be1 = (const float*)d_in[4];
  const float* m1  = (const float*)d_in[5];
  const float* v1  = (const float*)d_in[6];
  const float* w2  = (const float*)d_in[7];
  const float* b2  = (const float*)d_in[8];
  const float* g2  = (const float*)d_in[9];
  const float* be2 = (const float*)d_in[10];
  const float* m2  = (const float*)d_in[11];
  const float* v2  = (const float*)d_in[12];
  const float* w3  = (const float*)d_in[13];
  const float* b3  = (const float*)d_in[14];

  char* ws = (char*)d_ws;
  u16* h1  = (u16*)ws;                                  // 25.69 MB
  u16* w1s = (u16*)(ws + (size_t)PIX*CM*2);             // 64 KB
  u16* w3s = w1s + 32768;                               // 64 KB
  float* A1 = (float*)(w3s + 32768);
  float* B1 = A1 + 128;
  float* A2 = B1 + 128;
  float* B2 = A2 + 128;

  kprep<<<128, 256, 0, stream>>>(w1,b1,g1,be1,m1,v1,b2,g2,be2,m2,v2,w3,
                                 w1s,w3s,A1,B1,A2,B2);
  k1<<<PIX/128, 256, 0, stream>>>(x, w1s, A1, B1, h1);
  k23<<<NB*HW, 512, 0, stream>>>(h1, w2, A2, B2, w3s, b3, x, (float*)d_out);
}

// Round 2
// 284.106 us; speedup vs baseline: 1.0123x; 1.0123x over previous
//
#include <hip/hip_runtime.h>
#include <stdint.h>

typedef unsigned short u16;
typedef unsigned int   u32;
typedef __attribute__((ext_vector_type(8))) short bf16x8;
typedef __attribute__((ext_vector_type(4))) float f32x4;

#define EPS 1e-3f
#define NB 32
#define HW 56
#define CI 256
#define CM 128
#define PIX (NB*HW*HW)   // 100352

__device__ __forceinline__ float asf(u32 i){ union{u32 u; float f;} t; t.u=i; return t.f; }
__device__ __forceinline__ u16 f2bf(float f){
  union{float f; u32 u;} t; t.f = f;
  u32 x = t.u;
  return (u16)((x + 0x7fffu + ((x>>16)&1u)) >> 16);   // RNE
}

// ---------------- prep: MFMA-fragment-swizzled bf16 weights + BN fold ----------------
__global__ __launch_bounds__(256) void kprep(
    const float* __restrict__ w1, const float* __restrict__ b1, const float* __restrict__ g1,
    const float* __restrict__ be1, const float* __restrict__ m1, const float* __restrict__ v1,
    const float* __restrict__ b2, const float* __restrict__ g2,
    const float* __restrict__ be2, const float* __restrict__ m2, const float* __restrict__ v2,
    const float* __restrict__ w3,
    u16* __restrict__ w1s, u16* __restrict__ w3s,
    float* __restrict__ A1, float* __restrict__ B1,
    float* __restrict__ A2, float* __restrict__ B2){
  int i = blockIdx.x*256 + threadIdx.x;
  if (i < 32768){
    { // w1s: t(8) x kt(8) x lane(64) x 8
      int j = i & 7, lane = (i >> 3) & 63, kt = (i >> 9) & 7, t = i >> 12;
      int col = lane & 15, quad = lane >> 4;
      int n = t*16 + col, k = kt*32 + quad*8 + j;
      w1s[i] = f2bf(w1[k*CM + n]);
    }
    { // w3s: t(16) x kc(4) x lane(64) x 8
      int j = i & 7, lane = (i >> 3) & 63, kc = (i >> 9) & 3, t = i >> 11;
      int col = lane & 15, quad = lane >> 4;
      int n = t*16 + col, k = kc*32 + quad*8 + j;
      w3s[i] = f2bf(w3[k*CI + n]);
    }
  }
  if (i < 128){
    float s1 = g1[i] * rsqrtf(v1[i] + EPS);
    A1[i] = s1;
    B1[i] = b1[i]*s1 + be1[i] - m1[i]*s1;
    float s2 = g2[i] * rsqrtf(v2[i] + EPS);
    A2[i] = s2;
    B2[i] = b2[i]*s2 + be2[i] - m2[i]*s2;
  }
}

// ---------------- conv1 1x1 256->128 + BN + ReLU ----------------
// v3: single-shot full-K LDS tile. 512 thr (8 waves), M=128, N=128, K=256.
// Stage entire A-tile (128 px x 256 k, bf16, XOR-swizzled) in ONE pass with
// perfectly-coalesced float4 loads; one barrier; 64 MFMA/wave with no further
// barriers; epilogue repack overlaid in same LDS. 64 KB LDS -> 2 blocks/CU.
__global__ __launch_bounds__(512, 2) void k1(const float* __restrict__ x,
    const u16* __restrict__ w1s, const float* __restrict__ A1v,
    const float* __restrict__ B1v, u16* __restrict__ h1){
  __shared__ __align__(16) char smem[65536];     // A-tile [128][256] bf16, swizzled
  u16* outw = (u16*)smem;                        // epilogue overlay [128][136]
  const int tid  = threadIdx.x;
  const int lane = tid & 63, wv = tid >> 6;
  const int col  = lane & 15, quad = lane >> 4;
  const long p0 = (long)blockIdx.x * 128;

  // ---- stage: 16 coalesced float4 loads/thread -> bf16 -> swizzled ds_write_b64 ----
  // iter i: pixel m = i*8 + wv (so m&7 == wv, XOR term is thread-constant),
  // channel-quad c4 = lane; per wave per i: 64 lanes = one full 1 KB pixel row.
  {
    const int c4 = lane;
    const int swz = wv << 4;                      // (m&7)<<4 == wv<<4
    const float* xp = x + (p0 + wv)*CI + c4*4;
    char* dp = smem + (size_t)wv*512 + ((c4*8) ^ swz);
    #pragma unroll
    for (int i = 0; i < 16; i++){
      float4 v = *(const float4*)(xp + (size_t)i*8*CI);
      u32 lo = (u32)f2bf(v.x) | ((u32)f2bf(v.y) << 16);
      u32 hi = (u32)f2bf(v.z) | ((u32)f2bf(v.w) << 16);
      *(uint2*)(dp + (size_t)i*8*512) = make_uint2(lo, hi);
    }
  }
  // acc init while stores drain
  f32x4 acc[2][4];
  #pragma unroll
  for (int a = 0; a < 2; a++)
    #pragma unroll
    for (int b = 0; b < 4; b++){ acc[a][b][0]=0.f; acc[a][b][1]=0.f; acc[a][b][2]=0.f; acc[a][b][3]=0.f; }
  __syncthreads();   // sync1: A-tile staged

  // ---- MFMA: wave = m-group (wv>>1, 32 rows) x n-half (wv&1, 64 cols) ----
  const int mg = wv >> 1, nh = wv & 1;
  #pragma unroll
  for (int kt = 0; kt < 8; kt++){
    bf16x8 bfr[4], af[2];
    #pragma unroll
    for (int nt = 0; nt < 4; nt++)
      bfr[nt] = *(const bf16x8*)(w1s + (size_t)(((nh*4+nt)*8 + kt)*64 + lane)*8);
    #pragma unroll
    for (int mt = 0; mt < 2; mt++){
      int row = mg*32 + mt*16 + col;
      int byte = row*512 + ((kt*64 + quad*16) ^ ((row & 7) << 4));
      af[mt] = *(const bf16x8*)(smem + byte);
    }
    #pragma unroll
    for (int mt = 0; mt < 2; mt++)
      #pragma unroll
      for (int nt = 0; nt < 4; nt++)
        acc[mt][nt] = __builtin_amdgcn_mfma_f32_16x16x32_bf16(af[mt], bfr[nt], acc[mt][nt], 0, 0, 0);
  }
  __syncthreads();   // sync2: all A-tile reads done, region free for outw

  // ---- epilogue: BN + ReLU -> bf16, repack via LDS, coalesced vector store ----
  #pragma unroll
  for (int nt = 0; nt < 4; nt++){
    int n = nh*64 + nt*16 + col;
    float a1 = A1v[n], b1v = B1v[n];
    #pragma unroll
    for (int mt = 0; mt < 2; mt++)
      #pragma unroll
      for (int reg = 0; reg < 4; reg++){
        int m = mg*32 + mt*16 + quad*4 + reg;
        outw[m*136 + n] = f2bf(fmaxf(acc[mt][nt][reg]*a1 + b1v, 0.f));
      }
  }
  __syncthreads();   // sync3: outw ready
  #pragma unroll
  for (int r = 0; r < 4; r++){
    int idx = r*512 + tid;
    int m = idx >> 4, u4 = idx & 15;
    uint4 v = *(const uint4*)(outw + m*136 + u4*8);
    *(uint4*)(h1 + (p0+m)*CM + u4*8) = v;
  }
}

// ---------------- fused: grouped 3x3 + BN + ReLU + conv3 + bias + residual + ReLU ----------------
// v3: 512 threads, LDS overlay, half-0 residual prefetch only (xr2 removed: it
// spilled ~30 VGPR/thread -> 74 MB scratch writes in round 1), launch_bounds(512,2)
// so the VGPR cap is 128 (empirical: 2nd arg acts as min blocks/CU on this toolchain).
#define LSH1 132   // h1 tile stride (u16)
#define LSH2 136   // h2 tile stride (u16)
__global__ __launch_bounds__(512, 2) void k23(const u16* __restrict__ h1,
    const float* __restrict__ w2, const float* __restrict__ A2v,
    const float* __restrict__ B2v, const u16* __restrict__ w3s,
    const float* __restrict__ b3, const float* __restrict__ x,
    float* __restrict__ out){
  __shared__ __align__(16) char smem[3*HW*LSH1*2 + 4608*4];   // 44352 + 18432 = 62784
  u16*  tile = (u16*)smem;                                 // [3][56][132] bf16 (phase A/B)
  u16*  h2t  = (u16*)smem;                                 // [64][136] bf16 (overlay, phase B->C)
  float* pre = (float*)smem;                               // [64][132] f32 (overlay, epilogue)
  float* wsh = (float*)(smem + 3*HW*LSH1*2);               // [4608] f32 w2 (live whole kernel)

  const int tid = threadIdx.x;
  // XCD swizzle: grid 1792 = 8 * 224; XCD k gets 224 consecutive (img,row) blocks.
  const int bid = blockIdx.x;
  const int blk = (bid & 7)*224 + (bid >> 3);
  const int y0 = blk % HW;                 // row within image
  const long p0 = (long)blk * HW;          // first output pixel

  // ---- phase A: stage w2 + h1 rows y0-1..y0+1 ----
  for (int i = tid; i < 1152; i += 512)
    ((float4*)wsh)[i] = ((const float4*)w2)[i];
  #pragma unroll
  for (int r = 0; r < 3; r++){
    const int yy = y0 + r - 1;
    const bool valid = (yy >= 0 && yy < HW);
    const uint4* src = (const uint4*)(h1 + (long)(blk - y0 + yy)*HW*CM);
    for (int i = tid; i < 896; i += 512){
      uint4 v = make_uint4(0u,0u,0u,0u);
      if (valid) v = src[i];
      int px = i >> 4, ch = (i & 15)*8;
      u16* d = tile + (r*HW + px)*LSH1 + ch;
      *(uint2*)d     = make_uint2(v.x, v.y);
      *(uint2*)(d+4) = make_uint2(v.z, v.w);
    }
  }
  __syncthreads();   // sync1: tile+wsh staged

  // ---- residual prefetch, n-half 0: HBM streams under phase-B VALU ----
  float4 xr[4];
  #pragma unroll
  for (int it = 0; it < 4; it++){
    int i = tid + it*512;
    if (i < 1792){
      int m = i >> 5, f4 = i & 31;
      xr[it] = *(const float4*)(x + (p0+m)*CI + f4*4);
    }
  }

  // ---- phase B: grouped 3x3 conv, fp32 VALU, result kept in regs ----
  const int q = tid >> 6, pos = tid & 63;   // q: channel-eighth (wave id), pos: pixel
  const bool act = pos < HW;
  u16 ov[16];
  if (act){
    int ixo[3]; u32 mk[3];
    #pragma unroll
    for (int kx = 0; kx < 3; kx++){
      int c = pos + kx - 1;
      ixo[kx] = (c < 0 ? 0 : (c > 55 ? 55 : c)) * LSH1;
      mk[kx] = (c >= 0 && c < HW) ? 0xffffffffu : 0u;
    }
    #pragma unroll
    for (int gi = 0; gi < 4; gi++){
      const int cb = q*16 + gi*4;
      float a0=0.f, a1=0.f, a2=0.f, a3=0.f;
      #pragma unroll
      for (int ky = 0; ky < 3; ky++){
        const u16* trow = tile + ky*HW*LSH1 + cb;
        #pragma unroll
        for (int kx = 0; kx < 3; kx++){
          uint2 hv = *(const uint2*)(trow + ixo[kx]);
          u32 hx = hv.x & mk[kx], hy = hv.y & mk[kx];
          float i0 = asf(hx<<16), i1 = asf(hx&0xffff0000u);
          float i2 = asf(hy<<16), i3 = asf(hy&0xffff0000u);
          const float* wp = wsh + ((ky*3+kx)*4)*CM + cb;
          float4 w0  = *(const float4*)(wp);
          float4 w1v = *(const float4*)(wp+CM);
          float4 w2v = *(const float4*)(wp+2*CM);
          float4 w3v = *(const float4*)(wp+3*CM);
          a0 += i0*w0.x + i1*w1v.x + i2*w2v.x + i3*w3v.x;
          a1 += i0*w0.y + i1*w1v.y + i2*w2v.y + i3*w3v.y;
          a2 += i0*w0.z + i1*w1v.z + i2*w2v.z + i3*w3v.z;
          a3 += i0*w0.w + i1*w1v.w + i2*w2v.w + i3*w3v.w;
        }
      }
      float av[4] = {a0, a1, a2, a3};
      #pragma unroll
      for (int co = 0; co < 4; co++){
        int c = cb + co;
        ov[gi*4+co] = f2bf(fmaxf(av[co]*A2v[c] + B2v[c], 0.f));
      }
    }
  }
  __syncthreads();   // sync2: ALL tile reads complete (tile region now dead)

  // ---- write h2 into overlay region + zero pad rows ----
  if (act){
    uint4 pk0, pk1;
    pk0.x = (u32)ov[0]  | ((u32)ov[1]<<16);
    pk0.y = (u32)ov[2]  | ((u32)ov[3]<<16);
    pk0.z = (u32)ov[4]  | ((u32)ov[5]<<16);
    pk0.w = (u32)ov[6]  | ((u32)ov[7]<<16);
    pk1.x = (u32)ov[8]  | ((u32)ov[9]<<16);
    pk1.y = (u32)ov[10] | ((u32)ov[11]<<16);
    pk1.z = (u32)ov[12] | ((u32)ov[13]<<16);
    pk1.w = (u32)ov[14] | ((u32)ov[15]<<16);
    u16* op = h2t + pos*LSH2 + q*16;
    *(uint4*)op     = pk0;
    *(uint4*)(op+8) = pk1;
  }
  for (int i = tid; i < 544; i += 512)
    ((u32*)(h2t + 56*LSH2))[i] = 0u;
  __syncthreads();   // sync3: h2t ready

  // ---- phase C: conv3 MFMA. M=64, wave wv owns N=[wv*32, wv*32+32) ----
  const int lane = tid & 63, wv = tid >> 6;
  const int col  = lane & 15, quad = lane >> 4;
  f32x4 acc3[4][2];
  #pragma unroll
  for (int a = 0; a < 4; a++)
    #pragma unroll
    for (int b = 0; b < 2; b++){ acc3[a][b][0]=0.f; acc3[a][b][1]=0.f; acc3[a][b][2]=0.f; acc3[a][b][3]=0.f; }
  float bias[2];
  #pragma unroll
  for (int nt = 0; nt < 2; nt++) bias[nt] = b3[wv*32 + nt*16 + col];
  #pragma unroll
  for (int kc = 0; kc < 4; kc++){
    bf16x8 bfr[2], af[4];
    #pragma unroll
    for (int nt = 0; nt < 2; nt++)
      bfr[nt] = *(const bf16x8*)(w3s + (size_t)(((wv*2+nt)*4 + kc)*64 + lane)*8);
    #pragma unroll
    for (int mt = 0; mt < 4; mt++)
      af[mt] = *(const bf16x8*)(h2t + (mt*16 + col)*LSH2 + kc*32 + quad*8);
    #pragma unroll
    for (int mt = 0; mt < 4; mt++)
      #pragma unroll
      for (int nt = 0; nt < 2; nt++)
        acc3[mt][nt] = __builtin_amdgcn_mfma_f32_16x16x32_bf16(af[mt], bfr[nt], acc3[mt][nt], 0, 0, 0);
  }
  __syncthreads();   // sync4: h2t reads done (region free for pre overlay)

  // ---- epilogue: n-half 0 ----
  if (wv < 4){
    #pragma unroll
    for (int mt = 0; mt < 4; mt++)
      #pragma unroll
      for (int nt = 0; nt < 2; nt++)
        #pragma unroll
        for (int reg = 0; reg < 4; reg++){
          int m = mt*16 + quad*4 + reg;
          pre[m*132 + (wv&3)*32 + nt*16 + col] = acc3[mt][nt][reg] + bias[nt];
        }
  }
  __syncthreads();   // sync5: pre half-0 ready
  #pragma unroll
  for (int it = 0; it < 4; it++){
    int i = tid + it*512;
    if (i < 1792){
      int m = i >> 5, f4 = i & 31;
      float4 pv = *(const float4*)(pre + m*132 + f4*4);
      float4 o;
      o.x = fmaxf(pv.x + xr[it].x, 0.f);
      o.y = fmaxf(pv.y + xr[it].y, 0.f);
      o.z = fmaxf(pv.z + xr[it].z, 0.f);
      o.w = fmaxf(pv.w + xr[it].w, 0.f);
      *(float4*)(out + (p0+m)*CI + f4*4) = o;
    }
  }
  __syncthreads();   // sync6: pre half-0 consumed

  // ---- epilogue: n-half 1 (x loaded in-loop; no long-lived prefetch regs) ----
  if (wv >= 4){
    #pragma unroll
    for (int mt = 0; mt < 4; mt++)
      #pragma unroll
      for (int nt = 0; nt < 2; nt++)
        #pragma unroll
        for (int reg = 0; reg < 4; reg++){
          int m = mt*16 + quad*4 + reg;
          pre[m*132 + (wv&3)*32 + nt*16 + col] = acc3[mt][nt][reg] + bias[nt];
        }
  }
  __syncthreads();   // sync7: pre half-1 ready
  #pragma unroll
  for (int it = 0; it < 4; it++){
    int i = tid + it*512;
    if (i < 1792){
      int m = i >> 5, f4 = i & 31;
      float4 xv = *(const float4*)(x + (p0+m)*CI + 128 + f4*4);
      float4 pv = *(const float4*)(pre + m*132 + f4*4);
      float4 o;
      o.x = fmaxf(pv.x + xv.x, 0.f);
      o.y = fmaxf(pv.y + xv.y, 0.f);
      o.z = fmaxf(pv.z + xv.z, 0.f);
      o.w = fmaxf(pv.w + xv.w, 0.f);
      *(float4*)(out + (p0+m)*CI + 128 + f4*4) = o;
    }
  }
}

extern "C" void kernel_launch(void* const* d_in, const int* in_sizes, int n_in,
                              void* d_out, int out_size, void* d_ws, size_t ws_size,
                              hipStream_t stream){
  (void)in_sizes; (void)n_in; (void)out_size; (void)ws_size;
  const float* x   = (const float*)d_in[0];
  const float* w1  = (const float*)d_in[1];
  const float* b1  = (const float*)d_in[2];
  const float* g1  = (const float*)d_in[3];
  const float* be1 = (const float*)d_in[4];
  const float* m1  = (const float*)d_in[5];
  const float* v1  = (const float*)d_in[6];
  const float* w2  = (const float*)d_in[7];
  const float* b2  = (const float*)d_in[8];
  const float* g2  = (const float*)d_in[9];
  const float* be2 = (const float*)d_in[10];
  const float* m2  = (const float*)d_in[11];
  const float* v2  = (const float*)d_in[12];
  const float* w3  = (const float*)d_in[13];
  const float* b3  = (const float*)d_in[14];

  char* ws = (char*)d_ws;
  u16* h1  = (u16*)ws;                                  // 25.69 MB
  u16* w1s = (u16*)(ws + (size_t)PIX*CM*2);             // 64 KB
  u16* w3s = w1s + 32768;                               // 64 KB
  float* A1 = (float*)(w3s + 32768);
  float* B1 = A1 + 128;
  float* A2 = B1 + 128;
  float* B2 = A2 + 128;

  kprep<<<128, 256, 0, stream>>>(w1,b1,g1,be1,m1,v1,b2,g2,be2,m2,v2,w3,
                                 w1s,w3s,A1,B1,A2,B2);
  k1<<<PIX/128, 512, 0, stream>>>(x, w1s, A1, B1, h1);
  k23<<<NB*HW, 512, 0, stream>>>(h1, w2, A2, B2, w3s, b3, x, (float*)d_out);
}